// Round 1
// baseline (391.616 us; speedup 1.0000x reference)
//
#include <hip/hip_runtime.h>
#include <math.h>

#define H  1024
#define B  64
#define T  1024
#define BT (B*T)       // 65536
#define TC 16          // t-columns per tile
#define SPLIT 8        // blocks per b
#define CHUNKS 8       // chunks per block: T/(TC*SPLIT)

__device__ __forceinline__ float ex2(float x) { return __builtin_amdgcn_exp2f(x); }

// Main kernel: one block = (b, split). Stages [1024h x 16t] fp32 tile in LDS,
// computes score/max/min in the staging pass, exp+denom in-place, then
// accumulates out-partials in registers across 8 chunks.
__global__ __launch_bounds__(256, 2) void attn_main(const float* __restrict__ dec,
                                                    const float* __restrict__ enc,
                                                    float* __restrict__ ws)
{
    // element swizzle: value for logical t-offset c of row h lives at
    // col = (c + 5*(h>>1)) & 15  -> every phase is <=2-way bank conflicted.
    __shared__ float tile[H * TC];                       // 64 KB
    __shared__ __align__(16) float rbuf[3][4][TC];       // cross-wave partials
    __shared__ __align__(16) float prm[2][TC];           // per-t params

    const int tid   = threadIdx.x;
    const int split = blockIdx.x;
    const int b     = blockIdx.y;
    const int lane  = tid & 63;
    const int wave  = tid >> 6;

    // P1 mapping: thread (r, c4): rows h = r + 64*i, t-group 4*c4..4*c4+3
    const int r   = tid >> 2;          // 0..63
    const int c4  = tid & 3;           // 0..3
    const int cb1 = (5 * (r >> 1)) & 15;   // constant across i (160*i ≡ 0 mod 16)
    const int col0 = (4*c4 + 0 + cb1) & 15;
    const int col1 = (4*c4 + 1 + cb1) & 15;
    const int col2 = (4*c4 + 2 + cb1) & 15;
    const int col3 = (4*c4 + 3 + cb1) & 15;

    // P2 mapping: thread (t2, g): rows h = g + 16*i
    const int t2  = tid & 15;
    const int g   = tid >> 4;          // 0..15
    const int cb2 = (t2 + 5 * (g >> 1)) & 15;

    // P3 rotation: constant across k since 5*128k ≡ 0 mod 16
    const int cb3 = (5 * (tid >> 1)) & 15;

    float acc0 = 0.f, acc1 = 0.f, acc2 = 0.f, acc3 = 0.f;

    const float L2E = 1.44269504088896340736f;

    for (int c = 0; c < CHUNKS; ++c) {
        const int t0 = (split * CHUNKS + c) * TC;
        __syncthreads();   // tile reuse vs previous chunk's P3

        // ---------- P1: global -> LDS (swizzled) + dot + max + min ----------
        float4 s4  = make_float4(0.f, 0.f, 0.f, 0.f);
        float4 mx4 = make_float4(-INFINITY, -INFINITY, -INFINITY, -INFINITY);
        float4 mn4 = make_float4( INFINITY,  INFINITY,  INFINITY,  INFINITY);
        #pragma unroll
        for (int i = 0; i < 16; ++i) {
            const int h = r + 64*i;
            const float4 v = *(reinterpret_cast<const float4*>(enc + (size_t)h*BT + b*T + t0) + c4);
            const float dh = dec[b*H + h];
            s4.x = fmaf(v.x, dh, s4.x); s4.y = fmaf(v.y, dh, s4.y);
            s4.z = fmaf(v.z, dh, s4.z); s4.w = fmaf(v.w, dh, s4.w);
            mx4.x = fmaxf(mx4.x, v.x); mx4.y = fmaxf(mx4.y, v.y);
            mx4.z = fmaxf(mx4.z, v.z); mx4.w = fmaxf(mx4.w, v.w);
            mn4.x = fminf(mn4.x, v.x); mn4.y = fminf(mn4.y, v.y);
            mn4.z = fminf(mn4.z, v.z); mn4.w = fminf(mn4.w, v.w);
            const int base = h * TC;   // imm-offset friendly: r*16 + 1024*i
            tile[base + col0] = v.x;
            tile[base + col1] = v.y;
            tile[base + col2] = v.z;
            tile[base + col3] = v.w;
        }
        // wave-level reduce over r (stride-4 lane groups share c4)
        #pragma unroll
        for (int off = 4; off <= 32; off <<= 1) {
            s4.x += __shfl_xor(s4.x, off); s4.y += __shfl_xor(s4.y, off);
            s4.z += __shfl_xor(s4.z, off); s4.w += __shfl_xor(s4.w, off);
            mx4.x = fmaxf(mx4.x, __shfl_xor(mx4.x, off)); mx4.y = fmaxf(mx4.y, __shfl_xor(mx4.y, off));
            mx4.z = fmaxf(mx4.z, __shfl_xor(mx4.z, off)); mx4.w = fmaxf(mx4.w, __shfl_xor(mx4.w, off));
            mn4.x = fminf(mn4.x, __shfl_xor(mn4.x, off)); mn4.y = fminf(mn4.y, __shfl_xor(mn4.y, off));
            mn4.z = fminf(mn4.z, __shfl_xor(mn4.z, off)); mn4.w = fminf(mn4.w, __shfl_xor(mn4.w, off));
        }
        if (lane < 4) {   // lane == c4 group representative
            *reinterpret_cast<float4*>(&rbuf[0][wave][lane*4]) = s4;
            *reinterpret_cast<float4*>(&rbuf[1][wave][lane*4]) = mx4;
            *reinterpret_cast<float4*>(&rbuf[2][wave][lane*4]) = mn4;
        }
        __syncthreads();
        if (tid < TC) {
            const float s  = rbuf[0][0][tid] + rbuf[0][1][tid] + rbuf[0][2][tid] + rbuf[0][3][tid];
            const float mx = fmaxf(fmaxf(rbuf[1][0][tid], rbuf[1][1][tid]),
                                   fmaxf(rbuf[1][2][tid], rbuf[1][3][tid]));
            const float mn = fminf(fminf(rbuf[2][0][tid], rbuf[2][1][tid]),
                                   fminf(rbuf[2][2][tid], rbuf[2][3][tid]));
            const float m  = (s >= 0.f) ? s*mx : s*mn;   // true max_h(e*s)
            prm[0][tid] = s * L2E;
            prm[1][tid] = m * L2E;
        }
        __syncthreads();

        // ---------- P2: exp (in place) + denom ----------
        {
            const float s2 = prm[0][t2];
            const float m2 = prm[1][t2];
            const int b0 = g*TC + cb2;          // even i
            const int b1 = g*TC + (cb2 ^ 8);    // odd i (adding 8 mod 16 == xor 8)
            float dp = 0.f;
            #pragma unroll
            for (int i = 0; i < 64; ++i) {
                const int idx = ((i & 1) ? b1 : b0) + 256*i;   // (g+16i)*16 + col
                const float e  = tile[idx];
                const float ev = ex2(fmaf(e, s2, -m2));
                dp += ev;
                tile[idx] = ev;
            }
            dp += __shfl_xor(dp, 16);
            dp += __shfl_xor(dp, 32);
            if (lane < TC) rbuf[0][wave][lane] = dp;
        }
        __syncthreads();
        if (tid < TC) {
            const float d = rbuf[0][0][tid] + rbuf[0][1][tid] + rbuf[0][2][tid] + rbuf[0][3][tid];
            prm[0][tid] = 1.0f / d;
        }
        __syncthreads();

        // ---------- P3: out[h] partial += sum_t ex[h,t] * r_t ----------
        {
            const float4 r0 = *reinterpret_cast<const float4*>(&prm[0][0]);
            const float4 r1 = *reinterpret_cast<const float4*>(&prm[0][4]);
            const float4 r2 = *reinterpret_cast<const float4*>(&prm[0][8]);
            const float4 r3 = *reinterpret_cast<const float4*>(&prm[0][12]);
            const float rp[16] = { r0.x,r0.y,r0.z,r0.w, r1.x,r1.y,r1.z,r1.w,
                                   r2.x,r2.y,r2.z,r2.w, r3.x,r3.y,r3.z,r3.w };
            #pragma unroll
            for (int k = 0; k < 4; ++k) {
                const int h    = tid + 256*k;
                const int base = h * TC;
                float a = 0.f;
                int q = cb3;   // physical col for logical t = 0
                #pragma unroll
                for (int p = 0; p < 16; ++p) {
                    a = fmaf(tile[base + q], rp[p], a);
                    q = (q + 1) & 15;
                }
                if (k == 0) acc0 += a; else if (k == 1) acc1 += a;
                else if (k == 2) acc2 += a; else acc3 += a;
            }
        }
    }

    const size_t wbase = (size_t)(b * SPLIT + split) * H;
    ws[wbase + tid      ] = acc0;
    ws[wbase + tid + 256] = acc1;
    ws[wbase + tid + 512] = acc2;
    ws[wbase + tid + 768] = acc3;
}

// Reduce the 8 split-partials per (b,h).
__global__ __launch_bounds__(256) void attn_reduce(const float* __restrict__ ws,
                                                   float* __restrict__ out)
{
    const int idx = blockIdx.x * 256 + threadIdx.x;   // 0 .. B*H-1
    const int b = idx >> 10;
    const int h = idx & 1023;
    float s = 0.f;
    #pragma unroll
    for (int sp = 0; sp < SPLIT; ++sp)
        s += ws[(size_t)(b * SPLIT + sp) * H + h];
    out[idx] = s;
}

extern "C" void kernel_launch(void* const* d_in, const int* in_sizes, int n_in,
                              void* d_out, int out_size, void* d_ws, size_t ws_size,
                              hipStream_t stream)
{
    const float* dec = (const float*)d_in[0];   // [B,H]
    const float* enc = (const float*)d_in[1];   // [H,B,T]
    float* out = (float*)d_out;                 // [B,H]
    float* ws  = (float*)d_ws;                  // needs B*SPLIT*H*4 = 2 MB

    attn_main  <<<dim3(SPLIT, B), 256, 0, stream>>>(dec, enc, ws);
    attn_reduce<<<dim3((B*H)/256), 256, 0, stream>>>(ws, out);
}

// Round 2
// 377.725 us; speedup vs baseline: 1.0368x; 1.0368x over previous
//
#include <hip/hip_runtime.h>
#include <math.h>

#define H  1024
#define B  64
#define T  1024
#define BT (B*T)       // 65536
#define TC 32          // t-columns per block-chunk (128 B per row = full L2 line)
#define SPLIT 8        // blocks per b
#define CHUNKS 4       // T/(TC*SPLIT)
#define NT 512         // threads per block (8 waves)

__device__ __forceinline__ float ex2(float x) { return __builtin_amdgcn_exp2f(x); }

// One block = (b, split). Per chunk: 1024 rows x 32 t held ENTIRELY in
// registers (thread owns 16 rows x 4 t = 64 floats). Phases:
//   P1: coalesced 128B-line loads + dot/max/min (register)
//   P2: exp in place (register) + denominator reduce
//   P3: register fma accumulate of out partials
// LDS only holds tiny cross-wave reduction buffers (3.5 KB).
// VGPR budget ~116 -> __launch_bounds__(512,4) => 2 blocks/CU, cross-block
// overlap hides compute phases behind the other block's HBM streaming.
__global__ __launch_bounds__(NT, 4) void attn_main(const float* __restrict__ dec,
                                                   const float* __restrict__ enc,
                                                   float* __restrict__ ws)
{
    __shared__ float rbuf[3][8][TC];   // [qty][wave][t]  3 KB
    __shared__ float prm[2][TC];       // per-t params (s*log2e, m*log2e) / recip

    const int tid   = threadIdx.x;
    const int split = blockIdx.x;
    const int b     = blockIdx.y;
    const int lane  = tid & 63;
    const int wave  = tid >> 6;        // 0..7
    const int r     = tid >> 3;        // 0..63 ; rows h = r + 64*i, i=0..15
    const int c8    = tid & 7;         // float4 group: t_local = c8*4..c8*4+3

    const float L2E = 1.44269504088896340736f;

    float acc[16];
    #pragma unroll
    for (int i = 0; i < 16; ++i) acc[i] = 0.f;

    for (int c = 0; c < CHUNKS; ++c) {
        const int t0 = (split * CHUNKS + c) * TC;

        // ---------- P1: load (full 128B lines) + dot + max + min ----------
        float4 v[16];
        float4 s4  = make_float4(0.f, 0.f, 0.f, 0.f);
        float4 mx4 = make_float4(-INFINITY, -INFINITY, -INFINITY, -INFINITY);
        float4 mn4 = make_float4( INFINITY,  INFINITY,  INFINITY,  INFINITY);
        #pragma unroll
        for (int i = 0; i < 16; ++i) {
            const int h = r + 64*i;
            v[i] = *reinterpret_cast<const float4*>(enc + (size_t)h*BT + b*T + t0 + 4*c8);
            const float dh = dec[b*H + h];
            s4.x = fmaf(v[i].x, dh, s4.x); s4.y = fmaf(v[i].y, dh, s4.y);
            s4.z = fmaf(v[i].z, dh, s4.z); s4.w = fmaf(v[i].w, dh, s4.w);
            mx4.x = fmaxf(mx4.x, v[i].x); mx4.y = fmaxf(mx4.y, v[i].y);
            mx4.z = fmaxf(mx4.z, v[i].z); mx4.w = fmaxf(mx4.w, v[i].w);
            mn4.x = fminf(mn4.x, v[i].x); mn4.y = fminf(mn4.y, v[i].y);
            mn4.z = fminf(mn4.z, v[i].z); mn4.w = fminf(mn4.w, v[i].w);
        }
        // reduce over the wave's 8 r-groups (stride-8 lanes share c8)
        #pragma unroll
        for (int off = 8; off <= 32; off <<= 1) {
            s4.x += __shfl_xor(s4.x, off); s4.y += __shfl_xor(s4.y, off);
            s4.z += __shfl_xor(s4.z, off); s4.w += __shfl_xor(s4.w, off);
            mx4.x = fmaxf(mx4.x, __shfl_xor(mx4.x, off)); mx4.y = fmaxf(mx4.y, __shfl_xor(mx4.y, off));
            mx4.z = fmaxf(mx4.z, __shfl_xor(mx4.z, off)); mx4.w = fmaxf(mx4.w, __shfl_xor(mx4.w, off));
            mn4.x = fminf(mn4.x, __shfl_xor(mn4.x, off)); mn4.y = fminf(mn4.y, __shfl_xor(mn4.y, off));
            mn4.z = fminf(mn4.z, __shfl_xor(mn4.z, off)); mn4.w = fminf(mn4.w, __shfl_xor(mn4.w, off));
        }
        if (lane < 8) {   // lane == c8 representative
            *reinterpret_cast<float4*>(&rbuf[0][wave][lane*4]) = s4;
            *reinterpret_cast<float4*>(&rbuf[1][wave][lane*4]) = mx4;
            *reinterpret_cast<float4*>(&rbuf[2][wave][lane*4]) = mn4;
        }
        __syncthreads();
        if (tid < TC) {
            float s  = rbuf[0][0][tid];
            float mx = rbuf[1][0][tid];
            float mn = rbuf[2][0][tid];
            #pragma unroll
            for (int w = 1; w < 8; ++w) {
                s += rbuf[0][w][tid];
                mx = fmaxf(mx, rbuf[1][w][tid]);
                mn = fminf(mn, rbuf[2][w][tid]);
            }
            const float m = (s >= 0.f) ? s*mx : s*mn;   // true max_h(e*s)
            prm[0][tid] = s * L2E;
            prm[1][tid] = m * L2E;
        }
        __syncthreads();

        // ---------- P2: exp in place (registers) + denominator ----------
        {
            const float4 sv = *reinterpret_cast<const float4*>(&prm[0][c8*4]);
            const float4 mv = *reinterpret_cast<const float4*>(&prm[1][c8*4]);
            float4 d4 = make_float4(0.f, 0.f, 0.f, 0.f);
            #pragma unroll
            for (int i = 0; i < 16; ++i) {
                v[i].x = ex2(fmaf(v[i].x, sv.x, -mv.x));
                v[i].y = ex2(fmaf(v[i].y, sv.y, -mv.y));
                v[i].z = ex2(fmaf(v[i].z, sv.z, -mv.z));
                v[i].w = ex2(fmaf(v[i].w, sv.w, -mv.w));
                d4.x += v[i].x; d4.y += v[i].y; d4.z += v[i].z; d4.w += v[i].w;
            }
            #pragma unroll
            for (int off = 8; off <= 32; off <<= 1) {
                d4.x += __shfl_xor(d4.x, off); d4.y += __shfl_xor(d4.y, off);
                d4.z += __shfl_xor(d4.z, off); d4.w += __shfl_xor(d4.w, off);
            }
            if (lane < 8)
                *reinterpret_cast<float4*>(&rbuf[0][wave][lane*4]) = d4;
        }
        __syncthreads();
        if (tid < TC) {
            float d = rbuf[0][0][tid];
            #pragma unroll
            for (int w = 1; w < 8; ++w) d += rbuf[0][w][tid];
            prm[0][tid] = 1.0f / d;
        }
        __syncthreads();

        // ---------- P3: acc[i] += sum_t ev * r_t (registers only) ----------
        {
            const float4 rv = *reinterpret_cast<const float4*>(&prm[0][c8*4]);
            #pragma unroll
            for (int i = 0; i < 16; ++i) {
                acc[i] = fmaf(v[i].x, rv.x, acc[i]);
                acc[i] = fmaf(v[i].y, rv.y, acc[i]);
                acc[i] = fmaf(v[i].z, rv.z, acc[i]);
                acc[i] = fmaf(v[i].w, rv.w, acc[i]);
            }
        }
        __syncthreads();   // protect prm/rbuf before next chunk's writes
    }

    // reduce acc over the 8 c8-groups (lanes sharing r), then write partials
    #pragma unroll
    for (int i = 0; i < 16; ++i) {
        acc[i] += __shfl_xor(acc[i], 1);
        acc[i] += __shfl_xor(acc[i], 2);
        acc[i] += __shfl_xor(acc[i], 4);
    }
    const size_t wbase = (size_t)(b * SPLIT + split) * H;
    #pragma unroll
    for (int i = 0; i < 16; ++i) {
        if ((i >> 1) == c8)           // each lane stores 2 of the 16 rows
            ws[wbase + r + 64*i] = acc[i];
    }
}

// Reduce the 8 split-partials per (b,h).
__global__ __launch_bounds__(256) void attn_reduce(const float* __restrict__ ws,
                                                   float* __restrict__ out)
{
    const int idx = blockIdx.x * 256 + threadIdx.x;   // 0 .. B*H-1
    const int b = idx >> 10;
    const int h = idx & 1023;
    float s = 0.f;
    #pragma unroll
    for (int sp = 0; sp < SPLIT; ++sp)
        s += ws[(size_t)(b * SPLIT + sp) * H + h];
    out[idx] = s;
}

extern "C" void kernel_launch(void* const* d_in, const int* in_sizes, int n_in,
                              void* d_out, int out_size, void* d_ws, size_t ws_size,
                              hipStream_t stream)
{
    const float* dec = (const float*)d_in[0];   // [B,H]
    const float* enc = (const float*)d_in[1];   // [H,B,T]
    float* out = (float*)d_out;                 // [B,H]
    float* ws  = (float*)d_ws;                  // uses B*SPLIT*H*4 = 2 MB

    attn_main  <<<dim3(SPLIT, B), NT, 0, stream>>>(dec, enc, ws);
    attn_reduce<<<dim3((B*H)/256), 256, 0, stream>>>(ws, out);
}